// Round 6
// baseline (5656.364 us; speedup 1.0000x reference)
//
#include <hip/hip_runtime.h>
#include <hip/hip_bf16.h>

typedef __attribute__((ext_vector_type(4))) float f32x4;
typedef __attribute__((ext_vector_type(8))) short s16x8;
typedef __attribute__((ext_vector_type(4))) unsigned short u16x4;
typedef unsigned long long u64;
typedef unsigned int u32;

#define DEVFN static __device__ __forceinline__

constexpr int B_ = 256, T_ = 512, F_ = 64, H_ = 512;
constexpr int NB = 16;            // batch groups
constexpr int NS = 8;             // gate/h-col slices per group
constexpr int MT = B_ / NB;       // 16 batch rows per group
constexpr int NT = H_ / NS;       // 64 h cols per workgroup
constexpr int NGRID = NB * NS;    // 128 workgroups (<= 256 CUs: co-resident)
constexpr int NTHR = 256;
constexpr int C2 = H_ / 2;        // 256 u64 packets per h row
constexpr int SPIN_LIMIT = 2048;  // fast-path rounds before sticky escalation

DEVFN unsigned short f2bf(float f) {
  u32 u = __builtin_bit_cast(u32, f);
  u += 0x7fffu + ((u >> 16) & 1u);
  return (unsigned short)(u >> 16);
}

DEVFN float sigmoidf_(float x) { return 1.f / (1.f + __expf(-x)); }
DEVFN float tanhf_(float x) {
  float a = fabsf(x);
  float t = __expf(-2.f * a);
  float r = (1.f - t) / (1.f + t);
  return x < 0.f ? -r : r;
}

// Exchange v2: self-validating u64 packets {tag | 2 bf16}, published to TWO
// buffers: HpkF via plain stores (write-through L1 -> lands in the producer's
// L2; group peers share that L2 under the blockIdx%8 XCD round-robin, since
// all 8 members have blockIdx = gi mod 16) and HpkS via agent-scope atomics
// (coherent point; placement-independent). Consumers spin on HpkF with sc0
// loads (L1-bypass, L2-hit ~200cy); after SPIN_LIMIT rounds they stickily
// fall back to HpkS. Tags make staleness detectable, so the fast path is a
// pure performance heuristic: wrong XCD placement degrades speed, never
// correctness (G16). Poison tag 0xAAAAAAAA never matches t in [1,511].
__global__ __launch_bounds__(NTHR, 1)
void gru_scan(const float* __restrict__ x, const float* __restrict__ Wih,
              const float* __restrict__ Whh, const float* __restrict__ bih,
              const float* __restrict__ bhh, const float* __restrict__ hw,
              const float* __restrict__ hb, float* __restrict__ out,
              u64* __restrict__ HpkF, u64* __restrict__ HpkS)
{
  const int tid = threadIdx.x;
  const int lane = tid & 63;
  const int wv = tid >> 6;                    // wave id = col block (0..3)
  const int gi = (int)blockIdx.x & (NB - 1);  // batch group
  const int sj = (int)blockIdx.x >> 4;        // slice

  __shared__ __align__(16) unsigned char h_lds[2][MT * 1024];  // 32 KB, swizzled
  __shared__ __align__(16) unsigned char x_lds[2][MT * 128];   // 4 KB, swizzled

  const int frow = lane & 15;                 // A row = batch row; B col = gate col
  const int g8 = (lane >> 4) * 8;             // k sub-offset (elements)
  const int g16 = (lane >> 4) * 16;           // k sub-offset (bytes)
  const int gc = sj * NT + wv * 16 + frow;    // this lane's h/gate column

  // ---- persistent weight fragments in registers ----
  s16x8 whh_f[3][16];
  s16x8 wih_f[3][2];
#pragma unroll
  for (int g = 0; g < 3; ++g) {
    const float* wr = Whh + ((size_t)(g * H_ + gc)) * H_;
#pragma unroll
    for (int kk = 0; kk < 16; ++kk) {
      const float4 p0 = *(const float4*)(wr + kk * 32 + g8);
      const float4 p1 = *(const float4*)(wr + kk * 32 + g8 + 4);
      s16x8 f;
      f[0] = (short)f2bf(p0.x); f[1] = (short)f2bf(p0.y);
      f[2] = (short)f2bf(p0.z); f[3] = (short)f2bf(p0.w);
      f[4] = (short)f2bf(p1.x); f[5] = (short)f2bf(p1.y);
      f[6] = (short)f2bf(p1.z); f[7] = (short)f2bf(p1.w);
      whh_f[g][kk] = f;
    }
    const float* wr2 = Wih + ((size_t)(g * H_ + gc)) * F_;
#pragma unroll
    for (int k2 = 0; k2 < 2; ++k2) {
      const float4 p0 = *(const float4*)(wr2 + k2 * 32 + g8);
      const float4 p1 = *(const float4*)(wr2 + k2 * 32 + g8 + 4);
      s16x8 f;
      f[0] = (short)f2bf(p0.x); f[1] = (short)f2bf(p0.y);
      f[2] = (short)f2bf(p0.z); f[3] = (short)f2bf(p0.w);
      f[4] = (short)f2bf(p1.x); f[5] = (short)f2bf(p1.y);
      f[6] = (short)f2bf(p1.z); f[7] = (short)f2bf(p1.w);
      wih_f[g][k2] = f;
    }
  }

  const float b_r  = bih[gc] + bhh[gc];
  const float b_z  = bih[H_ + gc] + bhh[H_ + gc];
  const float b_in = bih[2 * H_ + gc];
  const float b_hn = bhh[2 * H_ + gc];
  const float hw_l = hw[gc];

  const int aswz = (frow & 7) << 4;            // LDS XOR swizzle for A reads
  const int c2own = sj * 32 + wv * 8 + (frow >> 1);  // own packet col index

  float hstate[4] = {0.f, 0.f, 0.f, 0.f};      // fp32 state, D-frag layout
  bool slow_mode = false;                      // sticky fallback (per wave)

  for (int t = 0; t < T_; ++t) {
    const int p = t & 1;
    // issue x(t) load early: its HBM latency hides under the gather spin
    const int xm = tid >> 4, xfs = tid & 15;
    const float4 xv =
        *(const float4*)(x + (((size_t)(gi * MT + xm)) * T_ + t) * F_ + xfs * 4);

    // ---- gather h(t) packets (tag == t): L2 fast path, agent fallback ----
    if (t > 0) {
      const size_t off = ((size_t)p * B_ + gi * MT) * C2 + tid;
      const u64* fsrc = HpkF + off;
      const u64* ssrc = HpkS + off;
      u64 pk[16];
      if (!slow_mode) {
#pragma unroll
        for (int i = 0; i < 8; ++i) {
          asm volatile(
              "global_load_dwordx2 %0, %2, off sc0\n\t"
              "global_load_dwordx2 %1, %2, off offset:2048 sc0"
              : "=&v"(pk[2 * i]), "=&v"(pk[2 * i + 1])
              : "v"(fsrc + i * 2 * C2)
              : "memory");
        }
        asm volatile("s_waitcnt vmcnt(0)" ::: "memory");
        __builtin_amdgcn_sched_barrier(0);
      } else {
#pragma unroll
        for (int q = 0; q < 16; ++q)
          pk[q] = __hip_atomic_load(ssrc + q * C2, __ATOMIC_RELAXED,
                                    __HIP_MEMORY_SCOPE_AGENT);
      }
      int spins = 0;
      for (;;) {
        bool bad = false;
#pragma unroll
        for (int q = 0; q < 16; ++q) bad |= ((u32)(pk[q] >> 32) != (u32)t);
        if (!__any(bad)) break;
        if (++spins == SPIN_LIMIT) slow_mode = true;  // sticky escalation
        __builtin_amdgcn_s_sleep(1);
        if (!slow_mode) {
#pragma unroll
          for (int i = 0; i < 8; ++i) {
            asm volatile(
                "global_load_dwordx2 %0, %2, off sc0\n\t"
                "global_load_dwordx2 %1, %2, off offset:2048 sc0"
                : "=&v"(pk[2 * i]), "=&v"(pk[2 * i + 1])
                : "v"(fsrc + i * 2 * C2)
                : "memory");
          }
          asm volatile("s_waitcnt vmcnt(0)" ::: "memory");
          __builtin_amdgcn_sched_barrier(0);
        } else {
#pragma unroll
          for (int q = 0; q < 16; ++q)
            pk[q] = __hip_atomic_load(ssrc + q * C2, __ATOMIC_RELAXED,
                                      __HIP_MEMORY_SCOPE_AGENT);
        }
      }
      // strip tags -> LDS (row q, byte col tid*4, swizzled)
#pragma unroll
      for (int q = 0; q < 16; ++q)
        *(u32*)(&h_lds[p][q * 1024 + ((tid * 4) ^ ((q & 7) << 4))]) =
            (u32)pk[q];
    }
    // ---- stage x(t) chunk -> LDS (bf16, swizzled, parity buffer) ----
    {
      u16x4 xb;
      xb[0] = f2bf(xv.x); xb[1] = f2bf(xv.y);
      xb[2] = f2bf(xv.z); xb[3] = f2bf(xv.w);
      *(u16x4*)(&x_lds[p][xm * 128 + ((xfs * 8) ^ ((xm & 7) << 4))]) = xb;
    }
    __syncthreads();   // the ONLY barrier per step

    // ---- gemm: gi (K=64) + gh (K=512), B operands from registers ----
    const char* xrow_ptr = (const char*)&x_lds[p][frow * 128];
    const char* hrow_ptr = (const char*)&h_lds[p][frow * 1024];
    f32x4 ar = {0.f, 0.f, 0.f, 0.f}, az = {0.f, 0.f, 0.f, 0.f};
    f32x4 anx = {0.f, 0.f, 0.f, 0.f}, anh = {0.f, 0.f, 0.f, 0.f};
#pragma unroll
    for (int k2 = 0; k2 < 2; ++k2) {
      const s16x8 a = *(const s16x8*)(xrow_ptr + ((k2 * 64 + g16) ^ aswz));
      ar  = __builtin_amdgcn_mfma_f32_16x16x32_bf16(a, wih_f[0][k2], ar, 0, 0, 0);
      az  = __builtin_amdgcn_mfma_f32_16x16x32_bf16(a, wih_f[1][k2], az, 0, 0, 0);
      anx = __builtin_amdgcn_mfma_f32_16x16x32_bf16(a, wih_f[2][k2], anx, 0, 0, 0);
    }
    if (t > 0) {
#pragma unroll
      for (int kk = 0; kk < 16; ++kk) {
        const s16x8 a = *(const s16x8*)(hrow_ptr + ((kk * 64 + g16) ^ aswz));
        ar  = __builtin_amdgcn_mfma_f32_16x16x32_bf16(a, whh_f[0][kk], ar, 0, 0, 0);
        az  = __builtin_amdgcn_mfma_f32_16x16x32_bf16(a, whh_f[1][kk], az, 0, 0, 0);
        anh = __builtin_amdgcn_mfma_f32_16x16x32_bf16(a, whh_f[2][kk], anh, 0, 0, 0);
      }
    }

    // ---- gates + state update (fp32 state in registers) ----
#pragma unroll
    for (int e = 0; e < 4; ++e) {
      const float rr = sigmoidf_(ar[e] + b_r);
      const float zz = sigmoidf_(az[e] + b_z);
      const float nn = tanhf_(anx[e] + b_in + rr * (anh[e] + b_hn));
      hstate[e] = (1.f - zz) * nn + zz * hstate[e];
    }

    // ---- publish h(t+1): fast (L2) + slow (coherent point), no fences ----
    if (t < T_ - 1) {
      unsigned short hbf[4];
#pragma unroll
      for (int e = 0; e < 4; ++e) hbf[e] = f2bf(hstate[e]);
      const size_t pbase = ((size_t)((t + 1) & 1) * B_ + gi * MT) * C2;
#pragma unroll
      for (int e = 0; e < 4; ++e) {
        const u32 other = (u32)__shfl_xor((int)hbf[e], 1);
        if (!(lane & 1)) {
          const int m = ((lane >> 4) << 2) + e;
          const u64 val = ((u64)(u32)(t + 1) << 32) |
                          (u64)((u32)hbf[e] | (other << 16));
          const size_t idx = pbase + (size_t)m * C2 + c2own;
          HpkF[idx] = val;   // plain store: write-through L1 -> shared L2
          __hip_atomic_store(HpkS + idx, val, __ATOMIC_RELAXED,
                             __HIP_MEMORY_SCOPE_AGENT);
        }
      }
    }
  }

  // ---- head: y[b] = sum_c h[b][c] * hw[c] + hb ----
  {
    float part[4];
#pragma unroll
    for (int e = 0; e < 4; ++e) part[e] = hstate[e] * hw_l;
#pragma unroll
    for (int mask = 1; mask < 16; mask <<= 1) {
#pragma unroll
      for (int e = 0; e < 4; ++e) part[e] += __shfl_xor(part[e], mask);
    }
    if ((lane & 15) == 0) {
      const float addb = (sj == 0 && wv == 0) ? hb[0] : 0.f;
#pragma unroll
      for (int e = 0; e < 4; ++e)
        atomicAdd(out + gi * MT + ((lane >> 4) << 2) + e, part[e] + addb);
    }
  }
}

extern "C" void kernel_launch(void* const* d_in, const int* in_sizes, int n_in,
                              void* d_out, int out_size, void* d_ws, size_t ws_size,
                              hipStream_t stream)
{
  const float* x   = (const float*)d_in[0];
  const float* Wih = (const float*)d_in[1];
  const float* Whh = (const float*)d_in[2];
  const float* bih = (const float*)d_in[3];
  const float* bhh = (const float*)d_in[4];
  const float* hw  = (const float*)d_in[5];
  const float* hb  = (const float*)d_in[6];
  float* out = (float*)d_out;
  u64* HpkF = (u64*)d_ws;                              // [2][256][256] fast (L2)
  u64* HpkS = (u64*)((char*)d_ws + (1u << 20));        // [2][256][256] slow (agent)

  hipMemsetAsync(d_out, 0, (size_t)out_size * sizeof(float), stream);

  gru_scan<<<dim3(NGRID), dim3(NTHR), 0, stream>>>(
      x, Wih, Whh, bih, bhh, hw, hb, out, HpkF, HpkS);
}

// Round 10
// 1797.842 us; speedup vs baseline: 3.1462x; 3.1462x over previous
//
#include <hip/hip_runtime.h>
#include <hip/hip_bf16.h>

typedef __attribute__((ext_vector_type(4))) float f32x4;
typedef __attribute__((ext_vector_type(8))) short s16x8;
typedef __attribute__((ext_vector_type(4))) unsigned short u16x4;
typedef unsigned long long u64;
typedef unsigned int u32;

#define DEVFN static __device__ __forceinline__

constexpr int B_ = 256, T_ = 512, F_ = 64, H_ = 512;
constexpr int NB = 16;            // batch groups
constexpr int NS = 8;             // gate/h-col slices per group
constexpr int MT = B_ / NB;       // 16 batch rows per group
constexpr int NT = H_ / NS;       // 64 h cols per workgroup
constexpr int NGRID = NB * NS;    // 128 workgroups (<= 256 CUs: co-resident)
constexpr int NTHR = 256;
constexpr int C2 = H_ / 2;        // 256 u64 packets per h row

DEVFN unsigned short f2bf(float f) {
  u32 u = __builtin_bit_cast(u32, f);
  u += 0x7fffu + ((u >> 16) & 1u);
  return (unsigned short)(u >> 16);
}

DEVFN float sigmoidf_(float x) { return 1.f / (1.f + __expf(-x)); }
DEVFN float tanhf_(float x) {
  float a = fabsf(x);
  float t = __expf(-2.f * a);
  float r = (1.f - t) / (1.f + t);
  return x < 0.f ? -r : r;
}

// Exchange v3 (= round-3 tagged packets + cheap sentinel detection):
// self-validating u64 packets {tag=t | 2 bf16} via relaxed agent-scope
// atomics, fire-and-forget (no flags, no drains). Gather is two-phase:
//   (1) lanes 0..7 poll ONE sentinel packet per peer slice (the peer's
//       last-issued packet) -> chip-wide poll traffic ~32 KB/round instead
//       of 4 MB/round (round-3's all-thread polling was MALL contention);
//   (2) full 16-packet burst + selective tag-retry (ordering-free: a
//       sentinel is only a hint; every packet still self-validates).
// Parity double-buffer; inductive safety: publishing t+2 (overwriting tag-t)
// requires having read all tag-(t+1), whose producers consumed tag-t.
// Poison tag 0xAAAAAAAA never matches t in [1,511] -> no ws init needed.
__global__ __launch_bounds__(NTHR, 1)
void gru_scan(const float* __restrict__ x, const float* __restrict__ Wih,
              const float* __restrict__ Whh, const float* __restrict__ bih,
              const float* __restrict__ bhh, const float* __restrict__ hw,
              const float* __restrict__ hb, float* __restrict__ out,
              u64* __restrict__ Hpk)
{
  const int tid = threadIdx.x;
  const int lane = tid & 63;
  const int wv = tid >> 6;                    // wave id = col block (0..3)
  const int gi = (int)blockIdx.x & (NB - 1);  // batch group
  const int sj = (int)blockIdx.x >> 4;        // slice

  __shared__ __align__(16) unsigned char h_lds[2][MT * 1024];  // 32 KB, swizzled
  __shared__ __align__(16) unsigned char x_lds[2][MT * 128];   // 4 KB, swizzled

  const int frow = lane & 15;                 // A row = batch row; B col = gate col
  const int g8 = (lane >> 4) * 8;             // k sub-offset (elements)
  const int g16 = (lane >> 4) * 16;           // k sub-offset (bytes)
  const int gc = sj * NT + wv * 16 + frow;    // this lane's h/gate column

  // ---- persistent weight fragments in registers ----
  s16x8 whh_f[3][16];
  s16x8 wih_f[3][2];
#pragma unroll
  for (int g = 0; g < 3; ++g) {
    const float* wr = Whh + ((size_t)(g * H_ + gc)) * H_;
#pragma unroll
    for (int kk = 0; kk < 16; ++kk) {
      const float4 p0 = *(const float4*)(wr + kk * 32 + g8);
      const float4 p1 = *(const float4*)(wr + kk * 32 + g8 + 4);
      s16x8 f;
      f[0] = (short)f2bf(p0.x); f[1] = (short)f2bf(p0.y);
      f[2] = (short)f2bf(p0.z); f[3] = (short)f2bf(p0.w);
      f[4] = (short)f2bf(p1.x); f[5] = (short)f2bf(p1.y);
      f[6] = (short)f2bf(p1.z); f[7] = (short)f2bf(p1.w);
      whh_f[g][kk] = f;
    }
    const float* wr2 = Wih + ((size_t)(g * H_ + gc)) * F_;
#pragma unroll
    for (int k2 = 0; k2 < 2; ++k2) {
      const float4 p0 = *(const float4*)(wr2 + k2 * 32 + g8);
      const float4 p1 = *(const float4*)(wr2 + k2 * 32 + g8 + 4);
      s16x8 f;
      f[0] = (short)f2bf(p0.x); f[1] = (short)f2bf(p0.y);
      f[2] = (short)f2bf(p0.z); f[3] = (short)f2bf(p0.w);
      f[4] = (short)f2bf(p1.x); f[5] = (short)f2bf(p1.y);
      f[6] = (short)f2bf(p1.z); f[7] = (short)f2bf(p1.w);
      wih_f[g][k2] = f;
    }
  }

  const float b_r  = bih[gc] + bhh[gc];
  const float b_z  = bih[H_ + gc] + bhh[H_ + gc];
  const float b_in = bih[2 * H_ + gc];
  const float b_hn = bhh[2 * H_ + gc];
  const float hw_l = hw[gc];

  const int aswz = (frow & 7) << 4;            // LDS XOR swizzle for A reads
  const int c2own = sj * 32 + wv * 8 + (frow >> 1);  // own packet col index

  float hstate[4] = {0.f, 0.f, 0.f, 0.f};      // fp32 state, D-frag layout

  for (int t = 0; t < T_; ++t) {
    const int p = t & 1;
    // issue x(t) load early: its HBM latency hides under the gather spin
    const int xm = tid >> 4, xfs = tid & 15;
    const float4 xv =
        *(const float4*)(x + (((size_t)(gi * MT + xm)) * T_ + t) * F_ + xfs * 4);

    // ---- gather h(t) packets (tag == t): sentinel wait, then burst ----
    if (t > 0) {
      const size_t base = ((size_t)p * B_ + gi * MT) * C2;
      // phase 1: lanes 0..7 poll peer lane's LAST-issued packet
      // (row 15, c2 = lane*32 + 31) -- a cheap hint, not a guarantee
      {
        const u64* sent = Hpk + base + (size_t)15 * C2 + (lane * 32 + 31);
        for (;;) {
          u64 sv = 0;
          if (lane < NS)
            sv = __hip_atomic_load(sent, __ATOMIC_RELAXED,
                                   __HIP_MEMORY_SCOPE_AGENT);
          if (__all(lane >= NS || ((u32)(sv >> 32) == (u32)t))) break;
          __builtin_amdgcn_s_sleep(1);
        }
      }
      // phase 2: burst all 16 packets, selective retry on tag mismatch
      const u64* src = Hpk + base + tid;
      u64 pk[16];
#pragma unroll
      for (int q = 0; q < 16; ++q)
        pk[q] = __hip_atomic_load(src + q * C2, __ATOMIC_RELAXED,
                                  __HIP_MEMORY_SCOPE_AGENT);
      for (;;) {
        bool bad = false;
#pragma unroll
        for (int q = 0; q < 16; ++q) bad |= ((u32)(pk[q] >> 32) != (u32)t);
        if (!__any(bad)) break;
        __builtin_amdgcn_s_sleep(1);
#pragma unroll
        for (int q = 0; q < 16; ++q)
          if ((u32)(pk[q] >> 32) != (u32)t)
            pk[q] = __hip_atomic_load(src + q * C2, __ATOMIC_RELAXED,
                                      __HIP_MEMORY_SCOPE_AGENT);
      }
      // strip tags -> LDS (row q, byte col tid*4, swizzled)
#pragma unroll
      for (int q = 0; q < 16; ++q)
        *(u32*)(&h_lds[p][q * 1024 + ((tid * 4) ^ ((q & 7) << 4))]) =
            (u32)pk[q];
    }
    // ---- stage x(t) chunk -> LDS (bf16, swizzled, parity buffer) ----
    {
      u16x4 xb;
      xb[0] = f2bf(xv.x); xb[1] = f2bf(xv.y);
      xb[2] = f2bf(xv.z); xb[3] = f2bf(xv.w);
      *(u16x4*)(&x_lds[p][xm * 128 + ((xfs * 8) ^ ((xm & 7) << 4))]) = xb;
    }
    __syncthreads();   // the ONLY barrier per step

    // ---- gemm: gi (K=64) + gh (K=512), B operands from registers ----
    const char* xrow_ptr = (const char*)&x_lds[p][frow * 128];
    const char* hrow_ptr = (const char*)&h_lds[p][frow * 1024];
    f32x4 ar = {0.f, 0.f, 0.f, 0.f}, az = {0.f, 0.f, 0.f, 0.f};
    f32x4 anx = {0.f, 0.f, 0.f, 0.f}, anh = {0.f, 0.f, 0.f, 0.f};
#pragma unroll
    for (int k2 = 0; k2 < 2; ++k2) {
      const s16x8 a = *(const s16x8*)(xrow_ptr + ((k2 * 64 + g16) ^ aswz));
      ar  = __builtin_amdgcn_mfma_f32_16x16x32_bf16(a, wih_f[0][k2], ar, 0, 0, 0);
      az  = __builtin_amdgcn_mfma_f32_16x16x32_bf16(a, wih_f[1][k2], az, 0, 0, 0);
      anx = __builtin_amdgcn_mfma_f32_16x16x32_bf16(a, wih_f[2][k2], anx, 0, 0, 0);
    }
    if (t > 0) {
#pragma unroll
      for (int kk = 0; kk < 16; ++kk) {
        const s16x8 a = *(const s16x8*)(hrow_ptr + ((kk * 64 + g16) ^ aswz));
        ar  = __builtin_amdgcn_mfma_f32_16x16x32_bf16(a, whh_f[0][kk], ar, 0, 0, 0);
        az  = __builtin_amdgcn_mfma_f32_16x16x32_bf16(a, whh_f[1][kk], az, 0, 0, 0);
        anh = __builtin_amdgcn_mfma_f32_16x16x32_bf16(a, whh_f[2][kk], anh, 0, 0, 0);
      }
    }

    // ---- gates + state update (fp32 state in registers) ----
#pragma unroll
    for (int e = 0; e < 4; ++e) {
      const float rr = sigmoidf_(ar[e] + b_r);
      const float zz = sigmoidf_(az[e] + b_z);
      const float nn = tanhf_(anx[e] + b_in + rr * (anh[e] + b_hn));
      hstate[e] = (1.f - zz) * nn + zz * hstate[e];
    }

    // ---- publish h(t+1) slice as tagged packets (fire-and-forget) ----
    if (t < T_ - 1) {
      unsigned short hbf[4];
#pragma unroll
      for (int e = 0; e < 4; ++e) hbf[e] = f2bf(hstate[e]);
      u64* dstbase = Hpk + ((size_t)((t + 1) & 1) * B_ + gi * MT) * C2;
#pragma unroll
      for (int e = 0; e < 4; ++e) {
        const u32 other = (u32)__shfl_xor((int)hbf[e], 1);
        if (!(lane & 1)) {
          const int m = ((lane >> 4) << 2) + e;
          const u64 val = ((u64)(u32)(t + 1) << 32) |
                          (u64)((u32)hbf[e] | (other << 16));
          __hip_atomic_store(dstbase + m * C2 + c2own, val, __ATOMIC_RELAXED,
                             __HIP_MEMORY_SCOPE_AGENT);
        }
      }
    }
  }

  // ---- head: y[b] = sum_c h[b][c] * hw[c] + hb ----
  {
    float part[4];
#pragma unroll
    for (int e = 0; e < 4; ++e) part[e] = hstate[e] * hw_l;
#pragma unroll
    for (int mask = 1; mask < 16; mask <<= 1) {
#pragma unroll
      for (int e = 0; e < 4; ++e) part[e] += __shfl_xor(part[e], mask);
    }
    if ((lane & 15) == 0) {
      const float addb = (sj == 0 && wv == 0) ? hb[0] : 0.f;
#pragma unroll
      for (int e = 0; e < 4; ++e)
        atomicAdd(out + gi * MT + ((lane >> 4) << 2) + e, part[e] + addb);
    }
  }
}

extern "C" void kernel_launch(void* const* d_in, const int* in_sizes, int n_in,
                              void* d_out, int out_size, void* d_ws, size_t ws_size,
                              hipStream_t stream)
{
  const float* x   = (const float*)d_in[0];
  const float* Wih = (const float*)d_in[1];
  const float* Whh = (const float*)d_in[2];
  const float* bih = (const float*)d_in[3];
  const float* bhh = (const float*)d_in[4];
  const float* hw  = (const float*)d_in[5];
  const float* hb  = (const float*)d_in[6];
  float* out = (float*)d_out;
  u64* Hpk = (u64*)d_ws;   // [2][256][256] tagged packets (1 MB); poison tag
                           // 0xAAAAAAAA never matches t in [1,511] -> no init

  hipMemsetAsync(d_out, 0, (size_t)out_size * sizeof(float), stream);

  gru_scan<<<dim3(NGRID), dim3(NTHR), 0, stream>>>(
      x, Wih, Whh, bih, bhh, hw, hb, out, Hpk);
}